// Round 1
// baseline (21.430 us; speedup 1.0000x reference)
//
#include <hip/hip_runtime.h>

// Problem constants (from reference setup_inputs)
#define BB 8
#define CC 3
#define HH 96
#define WW 320

// One wave (64 lanes) per box. Each wave computes the box's gaussian radius,
// sigma, center (redundantly per lane — all-broadcast loads, cheap), writes
// proj/offset (lane 0), then strides the (2*floor(r)+1)^2 window across its
// 64 lanes doing float-as-int atomicMax into the heat plane.
__global__ __launch_bounds__(256)
void rtm3d_heat_scatter(const float* __restrict__ bboxes,
                        const int* __restrict__ classes,
                        const int* __restrict__ img_id,
                        const unsigned char* __restrict__ noise_mask,
                        const int* __restrict__ max_radius_p,
                        float* __restrict__ heat,      // (B,C,H,W) pre-zeroed
                        float* __restrict__ proj_out,  // (N,2) stored as f32
                        float* __restrict__ off_out,   // (N,2)
                        int N) {
    int gid = blockIdx.x * blockDim.x + threadIdx.x;
    int box = gid >> 6;
    int lane = gid & 63;
    if (box >= N) return;

    float x1 = bboxes[box * 4 + 0];
    float y1 = bboxes[box * 4 + 1];
    float x2 = bboxes[box * 4 + 2];
    float y2 = bboxes[box * 4 + 3];

    // _gaussian_radius, faithful in f32
    const float mo = 0.7f;
    float h = ceilf(y2 - y1);
    float w = ceilf(x2 - x1);
    float b1 = h + w;
    float c1 = w * h * (1.0f - mo) / (1.0f + mo);
    float r1 = (b1 + sqrtf(b1 * b1 - 4.0f * c1)) * 0.5f;
    float b2 = 2.0f * (h + w);
    float c2 = (1.0f - mo) * w * h;
    float r2 = (b2 + sqrtf(b2 * b2 - 16.0f * c2)) * 0.5f;
    float b3 = -2.0f * mo * (h + w);
    float c3 = (mo - 1.0f) * w * h;
    float r3 = (b3 + sqrtf(b3 * b3 - 16.0f * mo * c3)) * 0.5f;
    float r = fminf(r1, fminf(r2, r3));

    float maxr = (float)(*max_radius_p);
    r = fminf(fmaxf(r, 0.0f), maxr);           // clip FIRST (ref clips radius)
    float sigma = (2.0f * r + 1.0f) / 6.0f;    // sigma from clipped radius
    float twoS2 = 2.0f * sigma * sigma;

    float cx = (x1 + x2) * 0.5f;
    float cy = (y1 + y2) * 0.5f;

    // proj = centers.astype(int32) -> trunc toward zero; offset = centers - proj
    int ipx = (int)cx;
    int ipy = (int)cy;
    if (lane == 0) {
        proj_out[box * 2 + 0] = (float)ipx;
        proj_out[box * 2 + 1] = (float)ipy;
        off_out[box * 2 + 0]  = cx - (float)ipx;
        off_out[box * 2 + 1]  = cy - (float)ipy;
    }

    int cls = classes[box];
    int img = img_id[box];
    bool nz = noise_mask[box] != 0;

    // inside iff |ox| <= r and |oy| <= r; ox,oy integers, r >= 0
    int ir = (int)r;                 // r >= 0 so trunc == floor
    int side = 2 * ir + 1;
    int M = side * side;

    float* __restrict__ plane = heat + (size_t)(img * CC + cls) * (HH * WW);

    for (int t = lane; t < M; t += 64) {
        int oy = t / side - ir;
        int ox = t - (t / side) * side - ir;
        float d2 = (float)(ox * ox + oy * oy);
        float val = expf(-d2 / twoS2);         // exp(-dist2 / (2*sigma^2))
        if (ox == 0 && oy == 0 && nz) val = 0.9999f;
        // tx = (centers + ox).astype(int32): f32 add then trunc toward zero
        int tx = (int)(cx + (float)ox);
        int ty = (int)(cy + (float)oy);
        if (tx >= 0 && tx < WW && ty >= 0 && ty < HH) {
            // val in (0,1]: int-bit ordering == float ordering for non-neg
            atomicMax((int*)&plane[ty * WW + tx], __float_as_int(val));
        }
    }
}

extern "C" void kernel_launch(void* const* d_in, const int* in_sizes, int n_in,
                              void* d_out, int out_size, void* d_ws, size_t ws_size,
                              hipStream_t stream) {
    const float* bboxes        = (const float*)d_in[1];
    const int* classes         = (const int*)d_in[2];
    const int* img_id          = (const int*)d_in[3];
    const unsigned char* noise = (const unsigned char*)d_in[4];
    const int* max_radius      = (const int*)d_in[5];

    const int N = in_sizes[2];                 // classes element count
    const int heat_elems = BB * CC * HH * WW;  // 737280

    float* heat = (float*)d_out;
    float* proj = heat + heat_elems;           // (N,2) as f32
    float* off  = proj + 2 * N;                // (N,2)

    // heat must be zero at the start of EVERY call (max-scatter identity)
    hipMemsetAsync(heat, 0, (size_t)heat_elems * sizeof(float), stream);

    // one wave per box: N*64 threads
    int threads = 256;
    int blocks = (N * 64 + threads - 1) / threads;
    rtm3d_heat_scatter<<<blocks, threads, 0, stream>>>(
        bboxes, classes, img_id, noise, max_radius,
        heat, proj, off, N);
}

// Round 2
// 20.857 us; speedup vs baseline: 1.0275x; 1.0275x over previous
//
#include <hip/hip_runtime.h>

// Problem constants (from reference setup_inputs)
#define BB 8
#define CC 3
#define HH 96
#define WW 320
#define HEAT_ELEMS (BB * CC * HH * WW)   // 737280

// Vectorized zero of the heat plane: 737280 floats = 184320 float4.
// Exactly 720 blocks x 256 threads, one 16B store per thread.
__global__ __launch_bounds__(256)
void rtm3d_zero_heat(float4* __restrict__ heat4) {
    int i = blockIdx.x * blockDim.x + threadIdx.x;
    heat4[i] = make_float4(0.f, 0.f, 0.f, 0.f);
}

// One wave (64 lanes) per box. Each wave computes the box's gaussian radius,
// sigma, center (redundantly per lane — broadcast loads, cheap), writes
// proj/offset (lane 0), then strides the (2*floor(r)+1)^2 window across its
// 64 lanes doing float-as-int atomicMax into the heat plane.
__global__ __launch_bounds__(256)
void rtm3d_heat_scatter(const float* __restrict__ bboxes,
                        const int* __restrict__ classes,
                        const int* __restrict__ img_id,
                        const unsigned char* __restrict__ noise_mask,
                        const int* __restrict__ max_radius_p,
                        float* __restrict__ heat,      // (B,C,H,W) pre-zeroed
                        float* __restrict__ proj_out,  // (N,2) stored as f32
                        float* __restrict__ off_out,   // (N,2)
                        int N) {
    int gid = blockIdx.x * blockDim.x + threadIdx.x;
    int box = gid >> 6;
    int lane = gid & 63;
    if (box >= N) return;

    float x1 = bboxes[box * 4 + 0];
    float y1 = bboxes[box * 4 + 1];
    float x2 = bboxes[box * 4 + 2];
    float y2 = bboxes[box * 4 + 3];

    // _gaussian_radius, faithful in f32
    const float mo = 0.7f;
    float h = ceilf(y2 - y1);
    float w = ceilf(x2 - x1);
    float b1 = h + w;
    float c1 = w * h * (1.0f - mo) / (1.0f + mo);
    float r1 = (b1 + sqrtf(b1 * b1 - 4.0f * c1)) * 0.5f;
    float b2 = 2.0f * (h + w);
    float c2 = (1.0f - mo) * w * h;
    float r2 = (b2 + sqrtf(b2 * b2 - 16.0f * c2)) * 0.5f;
    float b3 = -2.0f * mo * (h + w);
    float c3 = (mo - 1.0f) * w * h;
    float r3 = (b3 + sqrtf(b3 * b3 - 16.0f * mo * c3)) * 0.5f;
    float r = fminf(r1, fminf(r2, r3));

    float maxr = (float)(*max_radius_p);
    r = fminf(fmaxf(r, 0.0f), maxr);           // clip FIRST (ref clips radius)
    float sigma = (2.0f * r + 1.0f) / 6.0f;    // sigma from clipped radius
    float twoS2 = 2.0f * sigma * sigma;

    float cx = (x1 + x2) * 0.5f;
    float cy = (y1 + y2) * 0.5f;

    // proj = centers.astype(int32) -> trunc toward zero; offset = centers - proj
    int ipx = (int)cx;
    int ipy = (int)cy;
    if (lane == 0) {
        proj_out[box * 2 + 0] = (float)ipx;
        proj_out[box * 2 + 1] = (float)ipy;
        off_out[box * 2 + 0]  = cx - (float)ipx;
        off_out[box * 2 + 1]  = cy - (float)ipy;
    }

    int cls = classes[box];
    int img = img_id[box];
    bool nz = noise_mask[box] != 0;

    // inside iff |ox| <= r and |oy| <= r; ox,oy integers, r >= 0
    int ir = (int)r;                 // r >= 0 so trunc == floor
    int side = 2 * ir + 1;
    int M = side * side;

    float* __restrict__ plane = heat + (size_t)(img * CC + cls) * (HH * WW);

    for (int t = lane; t < M; t += 64) {
        int row = t / side;
        int oy = row - ir;
        int ox = t - row * side - ir;
        float d2 = (float)(ox * ox + oy * oy);
        float val = expf(-d2 / twoS2);         // exp(-dist2 / (2*sigma^2))
        if (ox == 0 && oy == 0 && nz) val = 0.9999f;
        // tx = (centers + ox).astype(int32): f32 add then trunc toward zero
        int tx = (int)(cx + (float)ox);
        int ty = (int)(cy + (float)oy);
        if (tx >= 0 && tx < WW && ty >= 0 && ty < HH) {
            // val in (0,1]: int-bit ordering == float ordering for non-neg
            atomicMax((int*)&plane[ty * WW + tx], __float_as_int(val));
        }
    }
}

extern "C" void kernel_launch(void* const* d_in, const int* in_sizes, int n_in,
                              void* d_out, int out_size, void* d_ws, size_t ws_size,
                              hipStream_t stream) {
    const float* bboxes        = (const float*)d_in[1];
    const int* classes         = (const int*)d_in[2];
    const int* img_id          = (const int*)d_in[3];
    const unsigned char* noise = (const unsigned char*)d_in[4];
    const int* max_radius      = (const int*)d_in[5];

    const int N = in_sizes[2];                 // classes element count

    float* heat = (float*)d_out;
    float* proj = heat + HEAT_ELEMS;           // (N,2) as f32
    float* off  = proj + 2 * N;                // (N,2)

    // heat must be zero at the start of EVERY call (max-scatter identity).
    // Custom float4 zero kernel: rocclr fillBuffer profiled at 39us/75GB/s.
    rtm3d_zero_heat<<<HEAT_ELEMS / 4 / 256, 256, 0, stream>>>((float4*)heat);

    // one wave per box: N*64 threads
    int threads = 256;
    int blocks = (N * 64 + threads - 1) / threads;
    rtm3d_heat_scatter<<<blocks, threads, 0, stream>>>(
        bboxes, classes, img_id, noise, max_radius,
        heat, proj, off, N);
}